// Round 12
// baseline (174.412 us; speedup 1.0000x reference)
//
#include <hip/hip_runtime.h>

// NeRF render, numerics contract (frozen from r8, PASSED):
//   sdt_i = fmul(sg, fsub(te,ts));  blocked-16 XLA cumsum:
//   s1[g] = within-16 fold of T0 (T0[g] = fold16 of sdt);  upper recursion
//   16384->1024->64->4 sequential folds + combine adds -> C2[16384];
//   C1[j] = (j>>4)? fadd(s1[j], C2[(j>>4)-1]) : s1[j];
//   C_i = g? fadd(fold16_incl(i), C1[g-1]) : fold16_incl(i);
//   excl_i = fsub(C_i, sdt_i);  expo = fsub(excl_i, el[ray]);
//   w = fmul(exp(-expo), fsub(1, exp(-sdt_i))).
// r20 = r19 resubmit (r19 died to container infra, no test verdict; source
// desk-checked: hdr staging indexing bijective+in-bounds, no divergent
// barrier, bounded loops). hdr coalescing: hdr (48MB, 60% of k_render
// bytes) was gathered at 96B lane stride; now staged via LDS -- 6 coalesced
// float4 loads/thread -> lds[slot][owner] (thread t owns float4s 6t..6t+5;
// pad 257), one barrier, conflict-free reads. Structure: 8 samples/thread,
// 2048 blocks. render math / scan / atomics: r10 verbatim.
// k_bottom / k_mid: byte-identical to r5/r6/r7/r10 (PASSED x4).

#define TPB 256
#define LDSF (256 * 17)      // k_bottom padded tile: 256 groups x 16 + pad

// update_dpp with old=0: masked/invalid lanes yield exactly 0.0f.
#define DPP0(SRC, CTRL, RMASK, BC) __int_as_float(__builtin_amdgcn_update_dpp( \
        0, __float_as_int(SRC), (CTRL), (RMASK), 0xf, (BC)))

// int max with DPP-shifted operand (old=0 identity for keys >= 0)
#define IMAXD(V, CTRL, RMASK, BC) { \
    int _tmp = __builtin_amdgcn_update_dpp(0, (V), (CTRL), (RMASK), 0xf, (BC)); \
    (V) = ((V) > _tmp) ? (V) : _tmp; }

#define ADD4(A, B) make_float4((A).x + (B).x, (A).y + (B).y, (A).z + (B).z, (A).w + (B).w)

// serial left-fold prefix within each 16-lane row, exact contract order.
__device__ __forceinline__ float fold16_dpp(float x) {
    float a = 0.0f;
    a = __fadd_rn(a, DPP0(x, 0x110 | 15, 0xf, true));
    a = __fadd_rn(a, DPP0(x, 0x110 | 14, 0xf, true));
    a = __fadd_rn(a, DPP0(x, 0x110 | 13, 0xf, true));
    a = __fadd_rn(a, DPP0(x, 0x110 | 12, 0xf, true));
    a = __fadd_rn(a, DPP0(x, 0x110 | 11, 0xf, true));
    a = __fadd_rn(a, DPP0(x, 0x110 | 10, 0xf, true));
    a = __fadd_rn(a, DPP0(x, 0x110 |  9, 0xf, true));
    a = __fadd_rn(a, DPP0(x, 0x110 |  8, 0xf, true));
    a = __fadd_rn(a, DPP0(x, 0x110 |  7, 0xf, true));
    a = __fadd_rn(a, DPP0(x, 0x110 |  6, 0xf, true));
    a = __fadd_rn(a, DPP0(x, 0x110 |  5, 0xf, true));
    a = __fadd_rn(a, DPP0(x, 0x110 |  4, 0xf, true));
    a = __fadd_rn(a, DPP0(x, 0x110 |  3, 0xf, true));
    a = __fadd_rn(a, DPP0(x, 0x110 |  2, 0xf, true));
    a = __fadd_rn(a, DPP0(x, 0x110 |  1, 0xf, true));
    a = __fadd_rn(a, x);
    return a;
}

// inclusive 64-lane scan (segment sums only; rounding-free path)
__device__ __forceinline__ float wscan(float v) {
    v = __fadd_rn(v, DPP0(v, 0x111, 0xf, true));   // row_shr:1
    v = __fadd_rn(v, DPP0(v, 0x112, 0xf, true));   // row_shr:2
    v = __fadd_rn(v, DPP0(v, 0x114, 0xf, true));   // row_shr:4
    v = __fadd_rn(v, DPP0(v, 0x118, 0xf, true));   // row_shr:8
    v = __fadd_rn(v, DPP0(v, 0x142, 0xa, false));  // row_bcast15 -> rows 1,3
    v = __fadd_rn(v, DPP0(v, 0x143, 0xc, false));  // row_bcast31 -> rows 2,3
    return v;
}

__device__ __forceinline__ float sdt_c(float tsv, float tev, float sgv) {
    return __fmul_rn(sgv, __fsub_rn(tev, tsv));
}

// block = one 4096-float tile: coalesced loads, sdt written coalesced,
// staged into padded LDS; thread t serially folds its 16-group from LDS.
__global__ void k_bottom(const float* __restrict__ ts, const float* __restrict__ te,
                         const float* __restrict__ sg, int S,
                         float* __restrict__ sdt, float* __restrict__ s1,
                         float* __restrict__ T1,
                         float4* __restrict__ out4, int n_rays) {
    __shared__ float lds[LDSF];
    int t = threadIdx.x;
    int tile = blockIdx.x;                    // grid = N1/TPB = 1024 tiles
    int gid = tile * TPB + t;
    if (gid < n_rays) out4[gid] = make_float4(0.f, 0.f, 0.f, 0.f);
    const float4* ts4 = (const float4*)ts;
    const float4* te4 = (const float4*)te;
    const float4* sg4 = (const float4*)sg;
    float4* sdt4 = (float4*)sdt;
    #pragma unroll
    for (int k = 0; k < 4; ++k) {
        int idx4 = tile * 1024 + k * 256 + t;  // lane-contiguous float4
        float4 a = ts4[idx4], b = te4[idx4], c = sg4[idx4];
        float4 xo;
        xo.x = sdt_c(a.x, b.x, c.x);
        xo.y = sdt_c(a.y, b.y, c.y);
        xo.z = sdt_c(a.z, b.z, c.z);
        xo.w = sdt_c(a.w, b.w, c.w);
        sdt4[idx4] = xo;                       // coalesced write
        int fl = (k * 256 + t) << 2;           // float idx within tile
        int g0 = fl >> 4, j0 = fl & 15;
        float* p = &lds[g0 * 17 + j0];
        p[0] = xo.x; p[1] = xo.y; p[2] = xo.z; p[3] = xo.w;
    }
    __syncthreads();
    float acc = 0.0f;
    #pragma unroll
    for (int j = 0; j < 16; ++j) acc = __fadd_rn(acc, lds[t * 17 + j]);
    float acc2 = fold16_dpp(acc);              // within-16 row fold -> s1
    int g = tile * 256 + t;
    s1[g] = acc2;
    if ((t & 15) == 15) T1[g >> 4] = acc2;
}

// single block, 1024 threads: scan T1[16384] through levels 2..base -> C2.
__global__ void k_mid(const float* __restrict__ T1, float* __restrict__ C2) {
    __shared__ float T2sh[1024];
    __shared__ float s3sh[1024];   // becomes C3 in place
    __shared__ float s4sh[64];     // becomes C4 in place
    __shared__ float T3sh[64];
    __shared__ float T4sh[4];
    __shared__ float C5sh[4];
    int t = threadIdx.x;
    const float4* T14 = (const float4*)T1;
    float s2l[16];
    float acc = 0.0f;
    #pragma unroll
    for (int k = 0; k < 4; ++k) {
        float4 v = T14[t * 4 + k];
        acc = __fadd_rn(acc, v.x); s2l[k * 4 + 0] = acc;
        acc = __fadd_rn(acc, v.y); s2l[k * 4 + 1] = acc;
        acc = __fadd_rn(acc, v.z); s2l[k * 4 + 2] = acc;
        acc = __fadd_rn(acc, v.w); s2l[k * 4 + 3] = acc;
    }
    T2sh[t] = acc;
    __syncthreads();
    if (t < 64) {                  // level 3
        float a3 = 0.0f;
        for (int j = 0; j < 16; ++j) { a3 = __fadd_rn(a3, T2sh[t * 16 + j]); s3sh[t * 16 + j] = a3; }
        T3sh[t] = a3;
    }
    __syncthreads();
    if (t < 4) {                   // level 4
        float a4 = 0.0f;
        for (int j = 0; j < 16; ++j) { a4 = __fadd_rn(a4, T3sh[t * 16 + j]); s4sh[t * 16 + j] = a4; }
        T4sh[t] = a4;
    }
    __syncthreads();
    if (t == 0) {                  // base fold of 4
        float c = 0.0f;
        for (int r = 0; r < 4; ++r) { c = __fadd_rn(c, T4sh[r]); C5sh[r] = c; }
    }
    __syncthreads();
    if (t < 64) {                  // C4 in place
        int r = t >> 4;
        float v4 = s4sh[t];
        s4sh[t] = r ? __fadd_rn(v4, C5sh[r - 1]) : v4;
    }
    __syncthreads();
    {                              // C3 in place
        int r = t >> 4;
        float v3 = s3sh[t];
        float c3 = r ? __fadd_rn(v3, s4sh[r - 1]) : v3;
        s3sh[t] = c3;
    }
    __syncthreads();
    float c3m = t ? s3sh[t - 1] : 0.0f;   // C3[t-1]
    float4* C24 = (float4*)C2;
    #pragma unroll
    for (int k = 0; k < 4; ++k) {
        float4 o;
        o.x = t ? __fadd_rn(s2l[k * 4 + 0], c3m) : s2l[k * 4 + 0];
        o.y = t ? __fadd_rn(s2l[k * 4 + 1], c3m) : s2l[k * 4 + 1];
        o.z = t ? __fadd_rn(s2l[k * 4 + 2], c3m) : s2l[k * 4 + 2];
        o.w = t ? __fadd_rn(s2l[k * 4 + 3], c3m) : s2l[k * 4 + 3];
        C24[t * 4 + k] = o;
    }
}

// wave-autonomous render, 8 samples/thread, hdr staged via LDS (coalesced).
__global__ void k_render(const int* __restrict__ ri, const float* __restrict__ sdt,
                         const float* __restrict__ s1, const float* __restrict__ C2,
                         const float* __restrict__ hdr,
                         int S, float* __restrict__ out) {
    // hdr staging: block covers 2048 samples = 1536 float4 of hdr.
    // Owner thread t consumes float4s 6t..6t+5 (24 floats = 6 float4).
    __shared__ float4 hsh[6 * 257];
    const int t = threadIdx.x & 63;           // lane
    const int tid = blockIdx.x * TPB + threadIdx.x;
    const int i0 = tid * 8;
    const bool valid = i0 < S;

    {
        const float4* h4 = (const float4*)hdr;
        const int hb = blockIdx.x * (TPB * 6);         // block base (float4)
        const int H4 = (S >> 2) * 3;                   // total hdr float4s
        #pragma unroll
        for (int k = 0; k < 6; ++k) {
            int f = k * TPB + threadIdx.x;             // 0..1535, coalesced
            float4 v = (hb + f < H4) ? h4[hb + f] : make_float4(0.f, 0.f, 0.f, 0.f);
            hsh[(f % 6) * 257 + (f / 6)] = v;
        }
    }

    // ---- per-thread vector loads (coalesced)
    float4 xa, xb; int4 ra, rb;
    if (valid) {
        xa = ((const float4*)sdt)[2 * tid];
        xb = ((const float4*)sdt)[2 * tid + 1];
        ra = ((const int4*)ri)[2 * tid];
        rb = ((const int4*)ri)[2 * tid + 1];
    } else {
        xa = xb = make_float4(0.f, 0.f, 0.f, 0.f);
        ra.x = ra.y = ra.z = ra.w = -1 - t;
        rb = ra;
    }
    int prb = 0;
    if ((t & 15) == 0 && i0 > 0 && valid) prb = ri[i0 - 1];
    float cj = 0.0f;
    {
        int j3 = (tid >> 1) - 1;
        if (valid && j3 >= 0) {
            float s1v = s1[j3];
            cj = (j3 >> 4) ? __fadd_rn(s1v, C2[(j3 >> 4) - 1]) : s1v;
        }
    }

    __syncthreads();
    float4 h0v = hsh[0 * 257 + threadIdx.x];
    float4 h1v = hsh[1 * 257 + threadIdx.x];
    float4 h2v = hsh[2 * 257 + threadIdx.x];
    float4 h3v = hsh[3 * 257 + threadIdx.x];
    float4 h4v = hsh[4 * 257 + threadIdx.x];
    float4 h5v = hsh[5 * 257 + threadIdx.x];

    // ---- previous-sample ray id
    int dpr = __builtin_amdgcn_update_dpp(0, rb.w, 0x111, 0xf, 0xf, true);
    int prev_r = dpr;
    if ((t & 15) == 0) prev_r = (i0 == 0 || !valid) ? (ra.x ^ 1) : prb;

    bool f0 = prev_r != ra.x;
    bool f1 = ra.y != ra.x, f2 = ra.z != ra.y, f3 = ra.w != ra.z;
    bool f4 = rb.x != ra.w, f5 = rb.y != rb.x, f6 = rb.z != rb.y, f7 = rb.w != rb.z;
    unsigned long long mask0 = __ballot(f0);

    // ---- fold16 (exact contract chain): group of 16 = 2 lanes, q = t&1.
    float p0 = __fadd_rn(0.0f, xa.x);
    float p1 = __fadd_rn(p0, xa.y);
    float p2 = __fadd_rn(p1, xa.z);
    float p3 = __fadd_rn(p2, xa.w);
    float p4 = __fadd_rn(p3, xb.x);
    float p5 = __fadd_rn(p4, xb.y);
    float p6 = __fadd_rn(p5, xb.z);
    float p7 = __fadd_rn(p6, xb.w);
    {
        float cin = DPP0(p7, 0x111, 0xf, true);   // lane-1's 8-total
        float n0 = __fadd_rn(cin, xa.x);
        float n1 = __fadd_rn(n0, xa.y);
        float n2 = __fadd_rn(n1, xa.z);
        float n3 = __fadd_rn(n2, xa.w);
        float n4 = __fadd_rn(n3, xb.x);
        float n5 = __fadd_rn(n4, xb.y);
        float n6 = __fadd_rn(n5, xb.z);
        float n7 = __fadd_rn(n6, xb.w);
        bool me = (t & 1) != 0;
        p0 = me ? n0 : p0; p1 = me ? n1 : p1;
        p2 = me ? n2 : p2; p3 = me ? n3 : p3;
        p4 = me ? n4 : p4; p5 = me ? n5 : p5;
        p6 = me ? n6 : p6; p7 = me ? n7 : p7;
    }

    int g = i0 >> 4;
    float e0 = __fsub_rn(g ? __fadd_rn(p0, cj) : p0, xa.x);
    float e1 = __fsub_rn(g ? __fadd_rn(p1, cj) : p1, xa.y);
    float e2 = __fsub_rn(g ? __fadd_rn(p2, cj) : p2, xa.z);
    float e3 = __fsub_rn(g ? __fadd_rn(p3, cj) : p3, xa.w);
    float e4 = __fsub_rn(g ? __fadd_rn(p4, cj) : p4, xb.x);
    float e5 = __fsub_rn(g ? __fadd_rn(p5, cj) : p5, xb.y);
    float e6 = __fsub_rn(g ? __fadd_rn(p6, cj) : p6, xb.z);
    float e7 = __fsub_rn(g ? __fadd_rn(p7, cj) : p7, xb.w);

    // ---- el for the wave-leading run (head in an earlier wave)
    float el_lead = 0.0f;
    if (!(mask0 & 1ull)) {                    // wave-uniform branch
        int wbs = (tid - t) * 8;              // wave's first sample
        int r0v = __builtin_amdgcn_readfirstlane(ra.x);
        int h0 = 0;
        for (int round = 0; round < 65536; ++round) {
            int idx = wbs - 1 - t - 64 * round;
            int rv = (idx >= 0) ? ri[idx] : (r0v ^ 1);
            unsigned long long mm = __ballot(rv != r0v);
            if (mm) {
                int lm = __ffsll((unsigned long long)mm) - 1;
                h0 = wbs - 64 * round - lm;
                break;
            }
        }
        float elv = 0.0f;
        if (t == 0) {                         // recompute C_head, frozen fold
            const float4* s4 = (const float4*)sdt;
            int gh = h0 >> 4, lh = h0 & 15;
            float4 q0 = s4[gh * 4 + 0], q1 = s4[gh * 4 + 1];
            float4 q2 = s4[gh * 4 + 2], q3 = s4[gh * 4 + 3];
            float vv[16] = { q0.x, q0.y, q0.z, q0.w, q1.x, q1.y, q1.z, q1.w,
                             q2.x, q2.y, q2.z, q2.w, q3.x, q3.y, q3.z, q3.w };
            float a2 = 0.0f, xl = 0.0f;
            #pragma unroll
            for (int j2 = 0; j2 < 16; ++j2) {
                if (j2 <= lh) { a2 = __fadd_rn(a2, vv[j2]); xl = vv[j2]; }
            }
            float Ch = a2;
            if (gh) {
                int j3b = gh - 1;
                float cjb = (j3b >> 4) ? __fadd_rn(s1[j3b], C2[(j3b >> 4) - 1]) : s1[j3b];
                Ch = __fadd_rn(a2, cjb);
            }
            elv = __fsub_rn(Ch, xl);
        }
        el_lead = __int_as_float(__builtin_amdgcn_readfirstlane(__float_as_int(elv)));
    }

    // ---- head-before flags
    bool hb0 = f0, hb1 = f1 | hb0, hb2 = f2 | hb1, hb3 = f3 | hb2;
    bool hb4 = f4 | hb3, hb5 = f5 | hb4, hb6 = f6 | hb5, hb7 = f7 | hb6;

    // ---- cross-lane source: last lane < me that contains a head
    int key = (valid && hb7) ? (t + 1) : 0;
    int sk = __shfl_up(key, 1, 64);
    if (t == 0) sk = 0;
    int M = sk;
    IMAXD(M, 0x111, 0xf, true)
    IMAXD(M, 0x112, 0xf, true)
    IMAXD(M, 0x114, 0xf, true)
    IMAXD(M, 0x118, 0xf, true)
    IMAXD(M, 0x142, 0xa, false)
    IMAXD(M, 0x143, 0xc, false)
    int src = M;
    int psrc = (src > 0) ? (src - 1) : t;

    float el7c = f7 ? e7 : f6 ? e6 : f5 ? e5 : f4 ? e4 :
                 f3 ? e3 : f2 ? e2 : f1 ? e1 : f0 ? e0 : 0.0f;
    float rel = __shfl(el7c, psrc, 64);
    float el_prev = (src > 0) ? rel : el_lead;

    float el0 = f0 ? e0 : el_prev;
    float el1 = f1 ? e1 : el0;
    float el2 = f2 ? e2 : el1;
    float el3 = f3 ? e3 : el2;
    float el4 = f4 ? e4 : el3;
    float el5 = f5 ? e5 : el4;
    float el6 = f6 ? e6 : el5;
    float el7 = f7 ? e7 : el6;

    // ---- weights (frozen arithmetic)
    float w0 = 0.f, w1 = 0.f, w2 = 0.f, w3 = 0.f;
    float w4 = 0.f, w5 = 0.f, w6 = 0.f, w7 = 0.f;
    if (valid) {
        w0 = __fmul_rn(__expf(-__fsub_rn(e0, el0)), __fsub_rn(1.0f, __expf(-xa.x)));
        w1 = __fmul_rn(__expf(-__fsub_rn(e1, el1)), __fsub_rn(1.0f, __expf(-xa.y)));
        w2 = __fmul_rn(__expf(-__fsub_rn(e2, el2)), __fsub_rn(1.0f, __expf(-xa.z)));
        w3 = __fmul_rn(__expf(-__fsub_rn(e3, el3)), __fsub_rn(1.0f, __expf(-xa.w)));
        w4 = __fmul_rn(__expf(-__fsub_rn(e4, el4)), __fsub_rn(1.0f, __expf(-xb.x)));
        w5 = __fmul_rn(__expf(-__fsub_rn(e5, el5)), __fsub_rn(1.0f, __expf(-xb.y)));
        w6 = __fmul_rn(__expf(-__fsub_rn(e6, el6)), __fsub_rn(1.0f, __expf(-xb.z)));
        w7 = __fmul_rn(__expf(-__fsub_rn(e7, el7)), __fsub_rn(1.0f, __expf(-xb.w)));
    }
    // hdr layout: s0:(h0.x,h0.y,h0.z) s1:(h0.w,h1.x,h1.y) s2:(h1.z,h1.w,h2.x)
    // s3:(h2.y,h2.z,h2.w) s4:(h3.x,h3.y,h3.z) s5:(h3.w,h4.x,h4.y)
    // s6:(h4.z,h4.w,h5.x) s7:(h5.y,h5.z,h5.w)
    float4 v0 = make_float4(w0, __fmul_rn(w0, h0v.x), __fmul_rn(w0, h0v.y), __fmul_rn(w0, h0v.z));
    float4 v1 = make_float4(w1, __fmul_rn(w1, h0v.w), __fmul_rn(w1, h1v.x), __fmul_rn(w1, h1v.y));
    float4 v2 = make_float4(w2, __fmul_rn(w2, h1v.z), __fmul_rn(w2, h1v.w), __fmul_rn(w2, h2v.x));
    float4 v3 = make_float4(w3, __fmul_rn(w3, h2v.y), __fmul_rn(w3, h2v.z), __fmul_rn(w3, h2v.w));
    float4 v4 = make_float4(w4, __fmul_rn(w4, h3v.x), __fmul_rn(w4, h3v.y), __fmul_rn(w4, h3v.z));
    float4 v5 = make_float4(w5, __fmul_rn(w5, h3v.w), __fmul_rn(w5, h4v.x), __fmul_rn(w5, h4v.y));
    float4 v6 = make_float4(w6, __fmul_rn(w6, h4v.z), __fmul_rn(w6, h4v.w), __fmul_rn(w6, h5v.x));
    float4 v7 = make_float4(w7, __fmul_rn(w7, h5v.y), __fmul_rn(w7, h5v.z), __fmul_rn(w7, h5v.w));

    float4 V0 = v0;
    float4 V1 = ADD4(V0, v1);
    float4 V2 = ADD4(V1, v2);
    float4 V3 = ADD4(V2, v3);
    float4 V4 = ADD4(V3, v4);
    float4 V5 = ADD4(V4, v5);
    float4 V6 = ADD4(V5, v6);
    float4 V7 = ADD4(V6, v7);

    float4 W;
    W.x = wscan(V7.x); W.y = wscan(V7.y); W.z = wscan(V7.z); W.w = wscan(V7.w);
    float4 E;
    E.x = __shfl_up(W.x, 1, 64);
    E.y = __shfl_up(W.y, 1, 64);
    E.z = __shfl_up(W.z, 1, 64);
    E.w = __shfl_up(W.w, 1, 64);
    if (t == 0) { E.x = 0.f; E.y = 0.f; E.z = 0.f; E.w = 0.f; }

    float4 Z = make_float4(0.f, 0.f, 0.f, 0.f);
    float4 B0 = f0 ? E : Z;
    float4 B1 = f1 ? ADD4(E, V0) : B0;
    float4 B2 = f2 ? ADD4(E, V1) : B1;
    float4 B3 = f3 ? ADD4(E, V2) : B2;
    float4 B4 = f4 ? ADD4(E, V3) : B3;
    float4 B5 = f5 ? ADD4(E, V4) : B4;
    float4 B6 = f6 ? ADD4(E, V5) : B5;
    float4 B7 = f7 ? ADD4(E, V6) : B6;

    float4 rbs;
    rbs.x = __shfl(B7.x, psrc, 64);
    rbs.y = __shfl(B7.y, psrc, 64);
    rbs.z = __shfl(B7.z, psrc, 64);
    rbs.w = __shfl(B7.w, psrc, 64);
    float4 bs_prev = (src > 0) ? rbs : Z;

    bool tl0 = f1, tl1 = f2, tl2 = f3, tl3 = f4, tl4 = f5, tl5 = f6, tl6 = f7;
    bool tl7 = (t < 63) ? (((mask0 >> (t + 1)) & 1ull) != 0ull) : true;

#define EMIT(K, TLK, RJ, VK) \
    if (valid && (TLK) && (RJ) >= 0) { \
        float4 bse = hb##K ? B##K : bs_prev; \
        float* o = out + 4 * (RJ); \
        atomicAdd(o + 0, (E.x + (VK).x) - bse.x); \
        atomicAdd(o + 1, (E.y + (VK).y) - bse.y); \
        atomicAdd(o + 2, (E.z + (VK).z) - bse.z); \
        atomicAdd(o + 3, (E.w + (VK).w) - bse.w); \
    }
    EMIT(0, tl0, ra.x, V0)
    EMIT(1, tl1, ra.y, V1)
    EMIT(2, tl2, ra.z, V2)
    EMIT(3, tl3, ra.w, V3)
    EMIT(4, tl4, rb.x, V4)
    EMIT(5, tl5, rb.y, V5)
    EMIT(6, tl6, rb.z, V6)
    EMIT(7, tl7, rb.w, V7)
#undef EMIT
}

extern "C" void kernel_launch(void* const* d_in, const int* in_sizes, int n_in,
                              void* d_out, int out_size, void* d_ws, size_t ws_size,
                              hipStream_t stream) {
    const float* ts  = (const float*)d_in[0];
    const float* te  = (const float*)d_in[1];
    const float* sg  = (const float*)d_in[2];
    const float* hdr = (const float*)d_in[3];
    const int*   ri  = (const int*)d_in[4];
    const int S      = in_sizes[0];          // 4194304 = 2^22
    const int n_rays = out_size / 4;
    const int N1 = S >> 4;                   // 262144
    const int N2 = N1 >> 4;                  // 16384

    char* w = (char*)d_ws;
    auto alloc = [&](size_t bytes) { char* p = w; w += (bytes + 255) & ~255ULL; return p; };
    float* sdt = (float*)alloc((size_t)S * 4);
    float* s1  = (float*)alloc((size_t)N1 * 4);
    float* T1  = (float*)alloc((size_t)N2 * 4);
    float* C2  = (float*)alloc((size_t)N2 * 4);

    k_bottom<<<dim3(N1 / TPB), dim3(TPB), 0, stream>>>(ts, te, sg, S, sdt, s1, T1,
                                                       (float4*)d_out, n_rays);
    k_mid   <<<dim3(1), dim3(1024), 0, stream>>>(T1, C2);
    k_render<<<dim3(S / (TPB * 8)), dim3(TPB), 0, stream>>>(ri, sdt, s1, C2, hdr,
                                                            S, (float*)d_out);
}

// Round 13
// 165.748 us; speedup vs baseline: 1.0523x; 1.0523x over previous
//
#include <hip/hip_runtime.h>

// NeRF render, numerics contract (frozen from r8, PASSED):
//   sdt_i = fmul(sg, fsub(te,ts));  blocked-16 XLA cumsum:
//   s1[g] = within-16 fold of T0 (T0[g] = fold16 of sdt);  upper recursion
//   16384->1024->64->4 sequential folds + combine adds -> C2[16384];
//   C1[j] = (j>>4)? fadd(s1[j], C2[(j>>4)-1]) : s1[j];
//   C_i = g? fadd(fold16_incl(i), C1[g-1]) : fold16_incl(i);
//   excl_i = fsub(C_i, sdt_i);  expo = fsub(excl_i, el[ray]);
//   w = fmul(exp(-expo), fsub(1, exp(-sdt_i))).
// r21: atomic->store split. Across 5 k_render variants WRITE_SIZE is
// invariant at 16.3MB for a 2MB output = 556K atomicAdds each writing a
// ~32B memory-side sector (cross-XCD atomics bypass per-XCD L2, done RMW
// at memory side, ~5/cycle chip-wide over 46us) => kernel is
// ATOMIC-THROUGHPUT-bound; that's why no load-side change ever moved it.
// With sorted ri, ~94% of runs are wave-private: piece with head-in-wave
// (hbK || src>0) AND real tail (K<7, or K==7 && t<63) has its ENTIRE run
// in this wave -> no other wave touches that ray -> plain float4 store
// over the zeroed output is exact. Boundary pieces keep atomics
// (556K -> ~70K atomic ops). hdr staging reverted (r12 regression, -6us):
// direct float4 loads as in r7/r10. 8 samples/thread, 2048 blocks.
// k_bottom / k_mid: byte-identical to r5/r6/r7/r10/r12 (PASSED x5).

#define TPB 256
#define LDSF (256 * 17)      // k_bottom padded tile: 256 groups x 16 + pad

// update_dpp with old=0: masked/invalid lanes yield exactly 0.0f.
#define DPP0(SRC, CTRL, RMASK, BC) __int_as_float(__builtin_amdgcn_update_dpp( \
        0, __float_as_int(SRC), (CTRL), (RMASK), 0xf, (BC)))

// int max with DPP-shifted operand (old=0 identity for keys >= 0)
#define IMAXD(V, CTRL, RMASK, BC) { \
    int _tmp = __builtin_amdgcn_update_dpp(0, (V), (CTRL), (RMASK), 0xf, (BC)); \
    (V) = ((V) > _tmp) ? (V) : _tmp; }

#define ADD4(A, B) make_float4((A).x + (B).x, (A).y + (B).y, (A).z + (B).z, (A).w + (B).w)

// serial left-fold prefix within each 16-lane row, exact contract order.
__device__ __forceinline__ float fold16_dpp(float x) {
    float a = 0.0f;
    a = __fadd_rn(a, DPP0(x, 0x110 | 15, 0xf, true));
    a = __fadd_rn(a, DPP0(x, 0x110 | 14, 0xf, true));
    a = __fadd_rn(a, DPP0(x, 0x110 | 13, 0xf, true));
    a = __fadd_rn(a, DPP0(x, 0x110 | 12, 0xf, true));
    a = __fadd_rn(a, DPP0(x, 0x110 | 11, 0xf, true));
    a = __fadd_rn(a, DPP0(x, 0x110 | 10, 0xf, true));
    a = __fadd_rn(a, DPP0(x, 0x110 |  9, 0xf, true));
    a = __fadd_rn(a, DPP0(x, 0x110 |  8, 0xf, true));
    a = __fadd_rn(a, DPP0(x, 0x110 |  7, 0xf, true));
    a = __fadd_rn(a, DPP0(x, 0x110 |  6, 0xf, true));
    a = __fadd_rn(a, DPP0(x, 0x110 |  5, 0xf, true));
    a = __fadd_rn(a, DPP0(x, 0x110 |  4, 0xf, true));
    a = __fadd_rn(a, DPP0(x, 0x110 |  3, 0xf, true));
    a = __fadd_rn(a, DPP0(x, 0x110 |  2, 0xf, true));
    a = __fadd_rn(a, DPP0(x, 0x110 |  1, 0xf, true));
    a = __fadd_rn(a, x);
    return a;
}

// inclusive 64-lane scan (segment sums only; rounding-free path)
__device__ __forceinline__ float wscan(float v) {
    v = __fadd_rn(v, DPP0(v, 0x111, 0xf, true));   // row_shr:1
    v = __fadd_rn(v, DPP0(v, 0x112, 0xf, true));   // row_shr:2
    v = __fadd_rn(v, DPP0(v, 0x114, 0xf, true));   // row_shr:4
    v = __fadd_rn(v, DPP0(v, 0x118, 0xf, true));   // row_shr:8
    v = __fadd_rn(v, DPP0(v, 0x142, 0xa, false));  // row_bcast15 -> rows 1,3
    v = __fadd_rn(v, DPP0(v, 0x143, 0xc, false));  // row_bcast31 -> rows 2,3
    return v;
}

__device__ __forceinline__ float sdt_c(float tsv, float tev, float sgv) {
    return __fmul_rn(sgv, __fsub_rn(tev, tsv));
}

// block = one 4096-float tile: coalesced loads, sdt written coalesced,
// staged into padded LDS; thread t serially folds its 16-group from LDS.
__global__ void k_bottom(const float* __restrict__ ts, const float* __restrict__ te,
                         const float* __restrict__ sg, int S,
                         float* __restrict__ sdt, float* __restrict__ s1,
                         float* __restrict__ T1,
                         float4* __restrict__ out4, int n_rays) {
    __shared__ float lds[LDSF];
    int t = threadIdx.x;
    int tile = blockIdx.x;                    // grid = N1/TPB = 1024 tiles
    int gid = tile * TPB + t;
    if (gid < n_rays) out4[gid] = make_float4(0.f, 0.f, 0.f, 0.f);
    const float4* ts4 = (const float4*)ts;
    const float4* te4 = (const float4*)te;
    const float4* sg4 = (const float4*)sg;
    float4* sdt4 = (float4*)sdt;
    #pragma unroll
    for (int k = 0; k < 4; ++k) {
        int idx4 = tile * 1024 + k * 256 + t;  // lane-contiguous float4
        float4 a = ts4[idx4], b = te4[idx4], c = sg4[idx4];
        float4 xo;
        xo.x = sdt_c(a.x, b.x, c.x);
        xo.y = sdt_c(a.y, b.y, c.y);
        xo.z = sdt_c(a.z, b.z, c.z);
        xo.w = sdt_c(a.w, b.w, c.w);
        sdt4[idx4] = xo;                       // coalesced write
        int fl = (k * 256 + t) << 2;           // float idx within tile
        int g0 = fl >> 4, j0 = fl & 15;
        float* p = &lds[g0 * 17 + j0];
        p[0] = xo.x; p[1] = xo.y; p[2] = xo.z; p[3] = xo.w;
    }
    __syncthreads();
    float acc = 0.0f;
    #pragma unroll
    for (int j = 0; j < 16; ++j) acc = __fadd_rn(acc, lds[t * 17 + j]);
    float acc2 = fold16_dpp(acc);              // within-16 row fold -> s1
    int g = tile * 256 + t;
    s1[g] = acc2;
    if ((t & 15) == 15) T1[g >> 4] = acc2;
}

// single block, 1024 threads: scan T1[16384] through levels 2..base -> C2.
__global__ void k_mid(const float* __restrict__ T1, float* __restrict__ C2) {
    __shared__ float T2sh[1024];
    __shared__ float s3sh[1024];   // becomes C3 in place
    __shared__ float s4sh[64];     // becomes C4 in place
    __shared__ float T3sh[64];
    __shared__ float T4sh[4];
    __shared__ float C5sh[4];
    int t = threadIdx.x;
    const float4* T14 = (const float4*)T1;
    float s2l[16];
    float acc = 0.0f;
    #pragma unroll
    for (int k = 0; k < 4; ++k) {
        float4 v = T14[t * 4 + k];
        acc = __fadd_rn(acc, v.x); s2l[k * 4 + 0] = acc;
        acc = __fadd_rn(acc, v.y); s2l[k * 4 + 1] = acc;
        acc = __fadd_rn(acc, v.z); s2l[k * 4 + 2] = acc;
        acc = __fadd_rn(acc, v.w); s2l[k * 4 + 3] = acc;
    }
    T2sh[t] = acc;
    __syncthreads();
    if (t < 64) {                  // level 3
        float a3 = 0.0f;
        for (int j = 0; j < 16; ++j) { a3 = __fadd_rn(a3, T2sh[t * 16 + j]); s3sh[t * 16 + j] = a3; }
        T3sh[t] = a3;
    }
    __syncthreads();
    if (t < 4) {                   // level 4
        float a4 = 0.0f;
        for (int j = 0; j < 16; ++j) { a4 = __fadd_rn(a4, T3sh[t * 16 + j]); s4sh[t * 16 + j] = a4; }
        T4sh[t] = a4;
    }
    __syncthreads();
    if (t == 0) {                  // base fold of 4
        float c = 0.0f;
        for (int r = 0; r < 4; ++r) { c = __fadd_rn(c, T4sh[r]); C5sh[r] = c; }
    }
    __syncthreads();
    if (t < 64) {                  // C4 in place
        int r = t >> 4;
        float v4 = s4sh[t];
        s4sh[t] = r ? __fadd_rn(v4, C5sh[r - 1]) : v4;
    }
    __syncthreads();
    {                              // C3 in place
        int r = t >> 4;
        float v3 = s3sh[t];
        float c3 = r ? __fadd_rn(v3, s4sh[r - 1]) : v3;
        s3sh[t] = c3;
    }
    __syncthreads();
    float c3m = t ? s3sh[t - 1] : 0.0f;   // C3[t-1]
    float4* C24 = (float4*)C2;
    #pragma unroll
    for (int k = 0; k < 4; ++k) {
        float4 o;
        o.x = t ? __fadd_rn(s2l[k * 4 + 0], c3m) : s2l[k * 4 + 0];
        o.y = t ? __fadd_rn(s2l[k * 4 + 1], c3m) : s2l[k * 4 + 1];
        o.z = t ? __fadd_rn(s2l[k * 4 + 2], c3m) : s2l[k * 4 + 2];
        o.w = t ? __fadd_rn(s2l[k * 4 + 3], c3m) : s2l[k * 4 + 3];
        C24[t * 4 + k] = o;
    }
}

// wave-autonomous render, 8 samples/thread; wave-private runs use plain
// float4 stores (exact; out pre-zeroed), only wave-spanning pieces atomic.
__global__ void k_render(const int* __restrict__ ri, const float* __restrict__ sdt,
                         const float* __restrict__ s1, const float* __restrict__ C2,
                         const float* __restrict__ hdr,
                         int S, float* __restrict__ out) {
    const int tid = blockIdx.x * TPB + threadIdx.x;
    const int t = threadIdx.x & 63;           // lane
    const int i0 = tid * 8;                   // first sample of this thread
    const bool valid = i0 < S;

    // ---- vector loads
    float4 xa, xb; int4 ra, rb;
    if (valid) {
        xa = ((const float4*)sdt)[2 * tid];
        xb = ((const float4*)sdt)[2 * tid + 1];
        ra = ((const int4*)ri)[2 * tid];
        rb = ((const int4*)ri)[2 * tid + 1];
    } else {
        xa = xb = make_float4(0.f, 0.f, 0.f, 0.f);
        ra.x = ra.y = ra.z = ra.w = -1 - t;
        rb = ra;
    }

    // ---- previous-sample ray id (DPP from lane-1's rb.w; 16-row boundary
    // lanes load ri[i0-1] from global, L1-hot)
    int dpr = __builtin_amdgcn_update_dpp(0, rb.w, 0x111, 0xf, 0xf, true);
    int prev_r = dpr;
    if ((t & 15) == 0) prev_r = (i0 == 0 || !valid) ? (ra.x ^ 1) : ri[i0 - 1];

    bool f0 = prev_r != ra.x;
    bool f1 = ra.y != ra.x, f2 = ra.z != ra.y, f3 = ra.w != ra.z;
    bool f4 = rb.x != ra.w, f5 = rb.y != rb.x, f6 = rb.z != rb.y, f7 = rb.w != rb.z;
    unsigned long long mask0 = __ballot(f0);

    // ---- fold16 (exact contract chain): group of 16 = 2 lanes, q = t&1.
    float p0 = __fadd_rn(0.0f, xa.x);
    float p1 = __fadd_rn(p0, xa.y);
    float p2 = __fadd_rn(p1, xa.z);
    float p3 = __fadd_rn(p2, xa.w);
    float p4 = __fadd_rn(p3, xb.x);
    float p5 = __fadd_rn(p4, xb.y);
    float p6 = __fadd_rn(p5, xb.z);
    float p7 = __fadd_rn(p6, xb.w);
    {
        float cin = DPP0(p7, 0x111, 0xf, true);   // lane-1's 8-total
        float n0 = __fadd_rn(cin, xa.x);
        float n1 = __fadd_rn(n0, xa.y);
        float n2 = __fadd_rn(n1, xa.z);
        float n3 = __fadd_rn(n2, xa.w);
        float n4 = __fadd_rn(n3, xb.x);
        float n5 = __fadd_rn(n4, xb.y);
        float n6 = __fadd_rn(n5, xb.z);
        float n7 = __fadd_rn(n6, xb.w);
        bool me = (t & 1) != 0;
        p0 = me ? n0 : p0; p1 = me ? n1 : p1;
        p2 = me ? n2 : p2; p3 = me ? n3 : p3;
        p4 = me ? n4 : p4; p5 = me ? n5 : p5;
        p6 = me ? n6 : p6; p7 = me ? n7 : p7;
    }

    int g = i0 >> 4;
    float cj = 0.0f;
    if (valid && g) {
        int j3 = g - 1;
        cj = (j3 >> 4) ? __fadd_rn(s1[j3], C2[(j3 >> 4) - 1]) : s1[j3];
    }
    float e0 = __fsub_rn(g ? __fadd_rn(p0, cj) : p0, xa.x);
    float e1 = __fsub_rn(g ? __fadd_rn(p1, cj) : p1, xa.y);
    float e2 = __fsub_rn(g ? __fadd_rn(p2, cj) : p2, xa.z);
    float e3 = __fsub_rn(g ? __fadd_rn(p3, cj) : p3, xa.w);
    float e4 = __fsub_rn(g ? __fadd_rn(p4, cj) : p4, xb.x);
    float e5 = __fsub_rn(g ? __fadd_rn(p5, cj) : p5, xb.y);
    float e6 = __fsub_rn(g ? __fadd_rn(p6, cj) : p6, xb.z);
    float e7 = __fsub_rn(g ? __fadd_rn(p7, cj) : p7, xb.w);

    // ---- el for the wave-leading run (head in an earlier wave)
    float el_lead = 0.0f;
    if (!(mask0 & 1ull)) {                    // wave-uniform branch
        int wbs = (tid - t) * 8;              // wave's first sample
        int r0v = __builtin_amdgcn_readfirstlane(ra.x);
        int h0 = 0;
        for (int round = 0; round < 65536; ++round) {
            int idx = wbs - 1 - t - 64 * round;
            int rv = (idx >= 0) ? ri[idx] : (r0v ^ 1);
            unsigned long long mm = __ballot(rv != r0v);
            if (mm) {
                int lm = __ffsll((unsigned long long)mm) - 1;
                h0 = wbs - 64 * round - lm;
                break;
            }
        }
        float elv = 0.0f;
        if (t == 0) {                         // recompute C_head, frozen fold
            const float4* s4 = (const float4*)sdt;
            int gh = h0 >> 4, lh = h0 & 15;
            float4 q0 = s4[gh * 4 + 0], q1 = s4[gh * 4 + 1];
            float4 q2 = s4[gh * 4 + 2], q3 = s4[gh * 4 + 3];
            float vv[16] = { q0.x, q0.y, q0.z, q0.w, q1.x, q1.y, q1.z, q1.w,
                             q2.x, q2.y, q2.z, q2.w, q3.x, q3.y, q3.z, q3.w };
            float a2 = 0.0f, xl = 0.0f;
            #pragma unroll
            for (int j2 = 0; j2 < 16; ++j2) {
                if (j2 <= lh) { a2 = __fadd_rn(a2, vv[j2]); xl = vv[j2]; }
            }
            float Ch = a2;
            if (gh) {
                int j3b = gh - 1;
                float cjb = (j3b >> 4) ? __fadd_rn(s1[j3b], C2[(j3b >> 4) - 1]) : s1[j3b];
                Ch = __fadd_rn(a2, cjb);
            }
            elv = __fsub_rn(Ch, xl);
        }
        el_lead = __int_as_float(__builtin_amdgcn_readfirstlane(__float_as_int(elv)));
    }

    // ---- head-before flags
    bool hb0 = f0, hb1 = f1 | hb0, hb2 = f2 | hb1, hb3 = f3 | hb2;
    bool hb4 = f4 | hb3, hb5 = f5 | hb4, hb6 = f6 | hb5, hb7 = f7 | hb6;

    // ---- cross-lane source: last lane < me that contains a head
    int key = (valid && hb7) ? (t + 1) : 0;
    int sk = __shfl_up(key, 1, 64);
    if (t == 0) sk = 0;
    int M = sk;
    IMAXD(M, 0x111, 0xf, true)
    IMAXD(M, 0x112, 0xf, true)
    IMAXD(M, 0x114, 0xf, true)
    IMAXD(M, 0x118, 0xf, true)
    IMAXD(M, 0x142, 0xa, false)
    IMAXD(M, 0x143, 0xc, false)
    int src = M;
    int psrc = (src > 0) ? (src - 1) : t;

    float el7c = f7 ? e7 : f6 ? e6 : f5 ? e5 : f4 ? e4 :
                 f3 ? e3 : f2 ? e2 : f1 ? e1 : f0 ? e0 : 0.0f;
    float rel = __shfl(el7c, psrc, 64);
    float el_prev = (src > 0) ? rel : el_lead;

    float el0 = f0 ? e0 : el_prev;
    float el1 = f1 ? e1 : el0;
    float el2 = f2 ? e2 : el1;
    float el3 = f3 ? e3 : el2;
    float el4 = f4 ? e4 : el3;
    float el5 = f5 ? e5 : el4;
    float el6 = f6 ? e6 : el5;
    float el7 = f7 ? e7 : el6;

    // ---- weights + hdr (direct coalesced-ish float4 loads, as r7/r10)
    float4 h0v, h1v, h2v, h3v, h4v, h5v;
    if (valid) {
        const float4* h4 = (const float4*)hdr;
        h0v = h4[6 * tid + 0]; h1v = h4[6 * tid + 1]; h2v = h4[6 * tid + 2];
        h3v = h4[6 * tid + 3]; h4v = h4[6 * tid + 4]; h5v = h4[6 * tid + 5];
    } else {
        h0v = h1v = h2v = h3v = h4v = h5v = make_float4(0.f, 0.f, 0.f, 0.f);
    }
    float w0 = 0.f, w1 = 0.f, w2 = 0.f, w3 = 0.f;
    float w4 = 0.f, w5 = 0.f, w6 = 0.f, w7 = 0.f;
    if (valid) {
        w0 = __fmul_rn(__expf(-__fsub_rn(e0, el0)), __fsub_rn(1.0f, __expf(-xa.x)));
        w1 = __fmul_rn(__expf(-__fsub_rn(e1, el1)), __fsub_rn(1.0f, __expf(-xa.y)));
        w2 = __fmul_rn(__expf(-__fsub_rn(e2, el2)), __fsub_rn(1.0f, __expf(-xa.z)));
        w3 = __fmul_rn(__expf(-__fsub_rn(e3, el3)), __fsub_rn(1.0f, __expf(-xa.w)));
        w4 = __fmul_rn(__expf(-__fsub_rn(e4, el4)), __fsub_rn(1.0f, __expf(-xb.x)));
        w5 = __fmul_rn(__expf(-__fsub_rn(e5, el5)), __fsub_rn(1.0f, __expf(-xb.y)));
        w6 = __fmul_rn(__expf(-__fsub_rn(e6, el6)), __fsub_rn(1.0f, __expf(-xb.z)));
        w7 = __fmul_rn(__expf(-__fsub_rn(e7, el7)), __fsub_rn(1.0f, __expf(-xb.w)));
    }
    float4 v0 = make_float4(w0, __fmul_rn(w0, h0v.x), __fmul_rn(w0, h0v.y), __fmul_rn(w0, h0v.z));
    float4 v1 = make_float4(w1, __fmul_rn(w1, h0v.w), __fmul_rn(w1, h1v.x), __fmul_rn(w1, h1v.y));
    float4 v2 = make_float4(w2, __fmul_rn(w2, h1v.z), __fmul_rn(w2, h1v.w), __fmul_rn(w2, h2v.x));
    float4 v3 = make_float4(w3, __fmul_rn(w3, h2v.y), __fmul_rn(w3, h2v.z), __fmul_rn(w3, h2v.w));
    float4 v4 = make_float4(w4, __fmul_rn(w4, h3v.x), __fmul_rn(w4, h3v.y), __fmul_rn(w4, h3v.z));
    float4 v5 = make_float4(w5, __fmul_rn(w5, h3v.w), __fmul_rn(w5, h4v.x), __fmul_rn(w5, h4v.y));
    float4 v6 = make_float4(w6, __fmul_rn(w6, h4v.z), __fmul_rn(w6, h4v.w), __fmul_rn(w6, h5v.x));
    float4 v7 = make_float4(w7, __fmul_rn(w7, h5v.y), __fmul_rn(w7, h5v.z), __fmul_rn(w7, h5v.w));

    float4 V0 = v0;
    float4 V1 = ADD4(V0, v1);
    float4 V2 = ADD4(V1, v2);
    float4 V3 = ADD4(V2, v3);
    float4 V4 = ADD4(V3, v4);
    float4 V5 = ADD4(V4, v5);
    float4 V6 = ADD4(V5, v6);
    float4 V7 = ADD4(V6, v7);

    float4 W;
    W.x = wscan(V7.x); W.y = wscan(V7.y); W.z = wscan(V7.z); W.w = wscan(V7.w);
    float4 E;
    E.x = __shfl_up(W.x, 1, 64);
    E.y = __shfl_up(W.y, 1, 64);
    E.z = __shfl_up(W.z, 1, 64);
    E.w = __shfl_up(W.w, 1, 64);
    if (t == 0) { E.x = 0.f; E.y = 0.f; E.z = 0.f; E.w = 0.f; }

    float4 Z = make_float4(0.f, 0.f, 0.f, 0.f);
    float4 B0 = f0 ? E : Z;
    float4 B1 = f1 ? ADD4(E, V0) : B0;
    float4 B2 = f2 ? ADD4(E, V1) : B1;
    float4 B3 = f3 ? ADD4(E, V2) : B2;
    float4 B4 = f4 ? ADD4(E, V3) : B3;
    float4 B5 = f5 ? ADD4(E, V4) : B4;
    float4 B6 = f6 ? ADD4(E, V5) : B5;
    float4 B7 = f7 ? ADD4(E, V6) : B6;

    float4 rbs;
    rbs.x = __shfl(B7.x, psrc, 64);
    rbs.y = __shfl(B7.y, psrc, 64);
    rbs.z = __shfl(B7.z, psrc, 64);
    rbs.w = __shfl(B7.w, psrc, 64);
    float4 bs_prev = (src > 0) ? rbs : Z;

    bool tl0 = f1, tl1 = f2, tl2 = f3, tl3 = f4, tl4 = f5, tl5 = f6, tl6 = f7;
    bool tl7 = (t < 63) ? (((mask0 >> (t + 1)) & 1ull) != 0ull) : true;
    // real-tail for piece 7: at t<63 the tl7 bit IS a real head of the next
    // lane; at t==63 the run may continue into the next wave -> atomic.
    bool rt7 = (t < 63);

    // piece is wave-private (store-exact) iff head-in-wave && real-tail:
    //   head-in-wave = hbK (head in-thread, real since f0 uses ri[i0-1])
    //                  || src>0 (head in an earlier lane of this wave)
#define EMIT(K, TLK, RJ, VK, RT) \
    if (valid && (TLK) && (RJ) >= 0) { \
        float4 bse = hb##K ? B##K : bs_prev; \
        float px = (E.x + (VK).x) - bse.x; \
        float py = (E.y + (VK).y) - bse.y; \
        float pz = (E.z + (VK).z) - bse.z; \
        float pw = (E.w + (VK).w) - bse.w; \
        float* o = out + 4 * (RJ); \
        bool priv = (hb##K || (src > 0)) && (RT); \
        if (priv) { \
            *(float4*)o = make_float4(px, py, pz, pw); \
        } else { \
            atomicAdd(o + 0, px); \
            atomicAdd(o + 1, py); \
            atomicAdd(o + 2, pz); \
            atomicAdd(o + 3, pw); \
        } \
    }
    EMIT(0, tl0, ra.x, V0, true)
    EMIT(1, tl1, ra.y, V1, true)
    EMIT(2, tl2, ra.z, V2, true)
    EMIT(3, tl3, ra.w, V3, true)
    EMIT(4, tl4, rb.x, V4, true)
    EMIT(5, tl5, rb.y, V5, true)
    EMIT(6, tl6, rb.z, V6, true)
    EMIT(7, tl7, rb.w, V7, rt7)
#undef EMIT
}

extern "C" void kernel_launch(void* const* d_in, const int* in_sizes, int n_in,
                              void* d_out, int out_size, void* d_ws, size_t ws_size,
                              hipStream_t stream) {
    const float* ts  = (const float*)d_in[0];
    const float* te  = (const float*)d_in[1];
    const float* sg  = (const float*)d_in[2];
    const float* hdr = (const float*)d_in[3];
    const int*   ri  = (const int*)d_in[4];
    const int S      = in_sizes[0];          // 4194304 = 2^22
    const int n_rays = out_size / 4;
    const int N1 = S >> 4;                   // 262144
    const int N2 = N1 >> 4;                  // 16384

    char* w = (char*)d_ws;
    auto alloc = [&](size_t bytes) { char* p = w; w += (bytes + 255) & ~255ULL; return p; };
    float* sdt = (float*)alloc((size_t)S * 4);
    float* s1  = (float*)alloc((size_t)N1 * 4);
    float* T1  = (float*)alloc((size_t)N2 * 4);
    float* C2  = (float*)alloc((size_t)N2 * 4);

    k_bottom<<<dim3(N1 / TPB), dim3(TPB), 0, stream>>>(ts, te, sg, S, sdt, s1, T1,
                                                       (float4*)d_out, n_rays);
    k_mid   <<<dim3(1), dim3(1024), 0, stream>>>(T1, C2);
    k_render<<<dim3(S / (TPB * 8)), dim3(TPB), 0, stream>>>(ri, sdt, s1, C2, hdr,
                                                            S, (float*)d_out);
}